// Round 3
// baseline (44225.143 us; speedup 1.0000x reference)
//
#include <hip/hip_runtime.h>
#include <math.h>

#define NB 256
#define NL 200
#define ND 512
#define SLICE 131072ul  // 512 k * 256 b floats

// ---- workspace layout (float offsets), all [k][b] transposed ----
// BIG[201][512][256]: slice u+1 = sessionT[u]; GRU writes sseqT[t] at slice t.
#define BIG_OFF   0ul
#define LG_OFF    26345472ul   // logits [200][256]
#define ATT_OFF   26396672ul   // att    [200][256]
#define VT_OFF    26447872ul   // vtT    [512][256]
#define HBUF_OFF  26578944ul   // h ping-pong [2][512][256]
#define HR_OFF    26841088ul   // r*h [512][256]
#define FLAGS_OFF 26972160ul   // 768 u32 epoch flags: gf[2][128], af1[2][128], af2[2][128]

__device__ __forceinline__ float sigmoidf_(float x) { return 1.0f / (1.0f + expf(-x)); }

// ---- grid barrier: per-block epoch flags; relaxed polls + one acquire fence ----
__device__ __forceinline__ void bar_arrive(unsigned* f, int slot, unsigned val) {
  __syncthreads();  // block's data stores are program-ordered before the release
  if (threadIdx.x == 0) {
    __hip_atomic_store(f + slot, val, __ATOMIC_RELEASE, __HIP_MEMORY_SCOPE_AGENT);
  }
}
__device__ __forceinline__ void bar_wait(const unsigned* f, unsigned val) {
  if (threadIdx.x < 128) {
    int guard = 0;
    while (__hip_atomic_load(f + threadIdx.x, __ATOMIC_RELAXED, __HIP_MEMORY_SCOPE_AGENT) < val) {
      __builtin_amdgcn_s_sleep(1);
      if (++guard > (1 << 22)) break;  // deadlock escape
    }
  }
  __syncthreads();
  __builtin_amdgcn_fence(__ATOMIC_ACQUIRE, "agent");
}

// ---- init: zero h ping-pong + flags (graph replays => must rerun each call) ----
__global__ void init_kernel(float* __restrict__ ws) {
  const int i = blockIdx.x * 256 + threadIdx.x;
  float* const hb = ws + HBUF_OFF;
  for (int j = i; j < 262144; j += 64 * 256) hb[j] = 0.0f;
  if (blockIdx.x == 0) {
    unsigned* const fl = (unsigned*)(ws + FLAGS_OFF);
    for (int j = threadIdx.x; j < 768; j += 256) fl[j] = 0u;
  }
}

// ---- transpose session [256][102400] -> BIG slices 1..200 as [tk][b] ----
__global__ __launch_bounds__(256) void transpose_kernel(const float* __restrict__ in,
                                                        float* __restrict__ ws) {
  __shared__ float tile[64][65];
  const int tx = threadIdx.x & 63, ty = threadIdx.x >> 6;
  const size_t tk0 = (size_t)blockIdx.x * 64;
  const int b0 = blockIdx.y * 64;
#pragma unroll
  for (int r = 0; r < 16; ++r) {
    const int bb = ty + 4 * r;
    tile[bb][tx] = in[(size_t)(b0 + bb) * 102400 + tk0 + tx];
  }
  __syncthreads();
  float* const big1 = ws + BIG_OFF + SLICE;  // slice 1 = sessionT[0]
#pragma unroll
  for (int r = 0; r < 16; ++r) {
    const int kk = ty + 4 * r;
    big1[(tk0 + kk) * 256 + b0 + tx] = tile[tx][kk];
  }
}

// ---- vtT[d][b] = sum_e w[d,e] * target[b,e] ----
__global__ __launch_bounds__(256) void vt_kernel(const float* __restrict__ w,
                                                 const float* __restrict__ tgt,
                                                 float* __restrict__ ws) {
  __shared__ float t_s[512];
  const int b = blockIdx.x, tid = threadIdx.x;
  for (int i = tid; i < 512; i += 256) t_s[i] = tgt[(size_t)b * 512 + i];
  __syncthreads();
  const int wv = tid >> 6, lane = tid & 63;
  for (int d = wv; d < 512; d += 4) {
    const float* const wr = w + (size_t)d * 512;
    const float4 a  = *(const float4*)(wr + lane * 8);
    const float4 a2 = *(const float4*)(wr + lane * 8 + 4);
    float s = a.x * t_s[lane * 8 + 0] + a.y * t_s[lane * 8 + 1] +
              a.z * t_s[lane * 8 + 2] + a.w * t_s[lane * 8 + 3] +
              a2.x * t_s[lane * 8 + 4] + a2.y * t_s[lane * 8 + 5] +
              a2.z * t_s[lane * 8 + 6] + a2.w * t_s[lane * 8 + 7];
    for (int off = 32; off > 0; off >>= 1) s += __shfl_xor(s, off);
    if (lane == 0) ws[VT_OFF + (size_t)d * 256 + b] = s;
  }
}

// ---- persistent GRU: 2 halves x 128 col-groups; coalesced [k][b] loads ----
__global__ __launch_bounds__(256) void gru_kernel(const float* __restrict__ wih,
                                                  const float* __restrict__ whh,
                                                  const float* __restrict__ bih,
                                                  const float* __restrict__ bhh,
                                                  float* __restrict__ ws) {
  __shared__ float wih_s[12 * 512];  // slot cc: gate=cc>>2, q=cc&3 -> row gate*512+c0+q
  __shared__ float whh_s[12 * 512];
  __shared__ float xp_s[12 * 128];
  __shared__ float hp_s[12 * 128];
  __shared__ float bih_s[12], bhh_s[12];

  const int bg = blockIdx.x >> 7;
  const int ng = blockIdx.x & 127;
  const int b0 = bg << 7;
  const int c0 = ng << 2;
  const int tid = threadIdx.x;

  for (int i = tid; i < 12 * 512; i += 256) {
    const int cc = i >> 9, kk = i & 511;
    const int grow = ((cc >> 2) << 9) + c0 + (cc & 3);
    wih_s[i] = wih[(size_t)grow * 512 + kk];
    whh_s[i] = whh[(size_t)grow * 512 + kk];
  }
  if (tid < 12) {
    const int grow = ((tid >> 2) << 9) + c0 + (tid & 3);
    bih_s[tid] = bih[grow];
    bhh_s[tid] = bhh[grow];
  }
  __syncthreads();

  float* const big = ws + BIG_OFF;
  float* const hbuf = ws + HBUF_OFF;
  unsigned* const gf = (unsigned*)(ws + FLAGS_OFF) + (bg << 7);

  const int l = tid & 63;
  const int wv = tid >> 6;
  const int cb = wv * 3;                  // this wave's 3 LDS col slots
  const int boff = b0 + 2 * l;            // rows 2l, 2l+1 (local) via float2
  const float* const w0x = wih_s + (size_t)(cb + 0) * 512;
  const float* const w1x = wih_s + (size_t)(cb + 1) * 512;
  const float* const w2x = wih_s + (size_t)(cb + 2) * 512;
  const float* const w0h = whh_s + (size_t)(cb + 0) * 512;
  const float* const w1h = whh_s + (size_t)(cb + 1) * 512;
  const float* const w2h = whh_s + (size_t)(cb + 2) * 512;

  for (int t = 0; t < NL; ++t) {
    // x-phase: sessionT[t] = BIG slice t+1 (independent of h -> before wait)
    const float* const xp = big + (size_t)(t + 1) * SLICE + boff;
    float a00 = 0, a01 = 0, a10 = 0, a11 = 0, a20 = 0, a21 = 0;
#pragma unroll 4
    for (int k = 0; k < 512; ++k) {
      const float2 xv = *(const float2*)(xp + (size_t)k * 256);
      const float u0 = w0x[k], u1 = w1x[k], u2 = w2x[k];
      a00 += xv.x * u0; a01 += xv.y * u0;
      a10 += xv.x * u1; a11 += xv.y * u1;
      a20 += xv.x * u2; a21 += xv.y * u2;
    }
    if (t > 0) bar_wait(gf, (unsigned)t);
    const float* const hbase = hbuf + (size_t)(t & 1) * SLICE;
    float h00 = 0, h01 = 0, h10 = 0, h11 = 0, h20 = 0, h21 = 0;
    if (t > 0) {
      const float* const hp = hbase + boff;
#pragma unroll 4
      for (int k = 0; k < 512; ++k) {
        const float2 hv = *(const float2*)(hp + (size_t)k * 256);
        const float u0 = w0h[k], u1 = w1h[k], u2 = w2h[k];
        h00 += hv.x * u0; h01 += hv.y * u0;
        h10 += hv.x * u1; h11 += hv.y * u1;
        h20 += hv.x * u2; h21 += hv.y * u2;
      }
    }
    *(float2*)(xp_s + (size_t)(cb + 0) * 128 + 2 * l) = make_float2(a00, a01);
    *(float2*)(xp_s + (size_t)(cb + 1) * 128 + 2 * l) = make_float2(a10, a11);
    *(float2*)(xp_s + (size_t)(cb + 2) * 128 + 2 * l) = make_float2(a20, a21);
    *(float2*)(hp_s + (size_t)(cb + 0) * 128 + 2 * l) = make_float2(h00, h01);
    *(float2*)(hp_s + (size_t)(cb + 1) * 128 + 2 * l) = make_float2(h10, h11);
    *(float2*)(hp_s + (size_t)(cb + 2) * 128 + 2 * l) = make_float2(h20, h21);
    __syncthreads();

    float* const hout = hbuf + (size_t)((t + 1) & 1) * SLICE;
#pragma unroll
    for (int rep = 0; rep < 2; ++rep) {
      const int idx = rep * 256 + tid;
      const int q = idx >> 7, b = idx & 127;
      const float xr = xp_s[(size_t)q * 128 + b] + bih_s[q];
      const float hr = hp_s[(size_t)q * 128 + b] + bhh_s[q];
      const float xz = xp_s[(size_t)(4 + q) * 128 + b] + bih_s[4 + q];
      const float hz = hp_s[(size_t)(4 + q) * 128 + b] + bhh_s[4 + q];
      const float xn = xp_s[(size_t)(8 + q) * 128 + b] + bih_s[8 + q];
      const float hn = hp_s[(size_t)(8 + q) * 128 + b] + bhh_s[8 + q];
      const float r = sigmoidf_(xr + hr);
      const float z = sigmoidf_(xz + hz);
      const float n = tanhf(xn + r * hn);
      const size_t o = (size_t)(c0 + q) * 256 + b0 + b;
      const float hprev = hbase[o];
      const float hnew = (1.0f - z) * n + z * hprev;
      hout[o] = hnew;
      big[(size_t)t * SLICE + o] = hnew;  // sseqT[t] over dead sessionT[t-1]
    }
    bar_arrive(gf, ng, (unsigned)(t + 1));
  }
}

// ---- attn1: logits[l][b] = sum_k sseqT[l][k][b] * vtT[k][b] ----
__global__ __launch_bounds__(256) void attn1_kernel(float* __restrict__ ws) {
  const int l = blockIdx.x, tid = threadIdx.x;
  const float* const sl = ws + BIG_OFF + (size_t)l * SLICE + tid;
  const float* const vtt = ws + VT_OFF + tid;
  float acc = 0.0f;
#pragma unroll 8
  for (int k = 0; k < 512; ++k)
    acc += sl[(size_t)k * 256] * vtt[(size_t)k * 256];
  ws[LG_OFF + (size_t)l * 256 + tid] = acc;
}

// ---- attn2: softmax over l per batch row; write attT[l][b] ----
__global__ __launch_bounds__(256) void attn2_kernel(float* __restrict__ ws) {
  __shared__ float red[8];
  const int b = blockIdx.x, tid = threadIdx.x;
  const float v = (tid < NL) ? ws[LG_OFF + (size_t)tid * 256 + b] : -3.0e38f;
  float m = v;
  for (int off = 32; off > 0; off >>= 1) m = fmaxf(m, __shfl_xor(m, off));
  if ((tid & 63) == 0) red[tid >> 6] = m;
  __syncthreads();
  m = fmaxf(fmaxf(red[0], red[1]), fmaxf(red[2], red[3]));
  const float e = (tid < NL) ? expf(v - m) : 0.0f;
  float s = e;
  for (int off = 32; off > 0; off >>= 1) s += __shfl_xor(s, off);
  __syncthreads();
  if ((tid & 63) == 0) red[4 + (tid >> 6)] = s;
  __syncthreads();
  s = red[4] + red[5] + red[6] + red[7];
  if (tid < NL) ws[ATT_OFF + (size_t)tid * 256 + b] = e / s;
}

// ---- persistent AUGRU: per-thread (2 rows x 1 col), no LDS staging ----
__global__ __launch_bounds__(256) void augru_kernel(const float* __restrict__ rw,
                                                    const float* __restrict__ rbias,
                                                    const float* __restrict__ uw,
                                                    const float* __restrict__ ubias,
                                                    const float* __restrict__ hw,
                                                    const float* __restrict__ hbias,
                                                    float* __restrict__ ws,
                                                    float* __restrict__ out) {
  __shared__ float wr_s[4 * 1024];
  __shared__ float wu_s[4 * 1024];
  __shared__ float wh_s[4 * 1024];
  __shared__ float rbs[4], ubs[4], hbs[4];

  const int bg = blockIdx.x >> 7, ng = blockIdx.x & 127;
  const int b0 = bg << 7, c0 = ng << 2;
  const int tid = threadIdx.x;
  for (int i = tid; i < 4 * 1024; i += 256) {
    const int q = i >> 10, kk = i & 1023;
    wr_s[i] = rw[(size_t)(c0 + q) * 1024 + kk];
    wu_s[i] = uw[(size_t)(c0 + q) * 1024 + kk];
    wh_s[i] = hw[(size_t)(c0 + q) * 1024 + kk];
  }
  if (tid < 4) {
    rbs[tid] = rbias[c0 + tid];
    ubs[tid] = ubias[c0 + tid];
    hbs[tid] = hbias[c0 + tid];
  }
  __syncthreads();

  float* const big = ws + BIG_OFF;
  float* const hbuf = ws + HBUF_OFF;
  float* const hrg = ws + HR_OFF;
  const float* const att = ws + ATT_OFF;
  unsigned* const fbase = (unsigned*)(ws + FLAGS_OFF);
  unsigned* const af1 = fbase + 256 + (bg << 7);
  unsigned* const af2 = fbase + 512 + (bg << 7);

  const int l = tid & 63, q = tid >> 6;   // rows 2l,2l+1; col q
  const int boff = b0 + 2 * l;
  const float* const wrq = wr_s + ((size_t)q << 10);
  const float* const wuq = wu_s + ((size_t)q << 10);
  const float* const whq = wh_s + ((size_t)q << 10);
  const size_t o = (size_t)(c0 + q) * 256 + boff;

  for (int t = 0; t < NL; ++t) {
    const float* const xp = big + (size_t)t * SLICE + boff;  // sseqT[t]
    // phase1 x-halves before the wait
    float pr0 = 0, pr1 = 0, pu0 = 0, pu1 = 0;
#pragma unroll 4
    for (int k = 0; k < 512; ++k) {
      const float2 xv = *(const float2*)(xp + (size_t)k * 256);
      const float ur = wrq[512 + k], uu = wuq[512 + k];
      pr0 += xv.x * ur; pr1 += xv.y * ur;
      pu0 += xv.x * uu; pu1 += xv.y * uu;
    }
    if (t > 0) bar_wait(af2, (unsigned)t);
    const float* const hbase = hbuf + (size_t)(t & 1) * SLICE;
    {
      const float* const hp = hbase + boff;
#pragma unroll 4
      for (int k = 0; k < 512; ++k) {
        const float2 hv = *(const float2*)(hp + (size_t)k * 256);
        const float ur = wrq[k], uu = wuq[k];
        pr0 += hv.x * ur; pr1 += hv.y * ur;
        pu0 += hv.x * uu; pu1 += hv.y * uu;
      }
    }
    const float rg0 = sigmoidf_(pr0 + rbs[q]);
    const float rg1 = sigmoidf_(pr1 + rbs[q]);
    const float ug0 = sigmoidf_(pu0 + ubs[q]);  // kept in regs for phase2
    const float ug1 = sigmoidf_(pu1 + ubs[q]);
    const float2 hcur = *(const float2*)(hbase + o);
    *(float2*)(hrg + o) = make_float2(rg0 * hcur.x, rg1 * hcur.y);
    bar_arrive(af1, ng, (unsigned)(t + 1));

    // phase2 x-halves before the wait on r*h
    float ph0 = 0, ph1 = 0;
#pragma unroll 4
    for (int k = 0; k < 512; ++k) {
      const float2 xv = *(const float2*)(xp + (size_t)k * 256);
      const float uh = whq[512 + k];
      ph0 += xv.x * uh; ph1 += xv.y * uh;
    }
    bar_wait(af1, (unsigned)(t + 1));
    {
      const float* const hrp = hrg + boff;
#pragma unroll 4
      for (int k = 0; k < 512; ++k) {
        const float2 rv = *(const float2*)(hrp + (size_t)k * 256);
        const float uh = whq[k];
        ph0 += rv.x * uh; ph1 += rv.y * uh;
      }
    }
    const float hh0 = tanhf(ph0 + hbs[q]);
    const float hh1 = tanhf(ph1 + hbs[q]);
    const float2 av = *(const float2*)(att + (size_t)t * 256 + boff);
    const float u0 = av.x * ug0, u1 = av.y * ug1;
    const float hn0 = (1.0f - u0) * hcur.x + u0 * hh0;
    const float hn1 = (1.0f - u1) * hcur.y + u1 * hh1;
    if (t == NL - 1) {
      out[(size_t)boff * 512 + c0 + q] = hn0;
      out[(size_t)(boff + 1) * 512 + c0 + q] = hn1;
    } else {
      *(float2*)(hbuf + (size_t)((t + 1) & 1) * SLICE + o) = make_float2(hn0, hn1);
    }
    bar_arrive(af2, ng, (unsigned)(t + 1));
  }
}

extern "C" void kernel_launch(void* const* d_in, const int* in_sizes, int n_in,
                              void* d_out, int out_size, void* d_ws, size_t ws_size,
                              hipStream_t stream) {
  (void)in_sizes; (void)n_in; (void)out_size; (void)ws_size;
  const float* session = (const float*)d_in[0];
  const float* target  = (const float*)d_in[1];
  const float* w       = (const float*)d_in[2];
  const float* wih     = (const float*)d_in[3];
  const float* whh     = (const float*)d_in[4];
  const float* bih     = (const float*)d_in[5];
  const float* bhh     = (const float*)d_in[6];
  const float* rw      = (const float*)d_in[7];
  const float* rb      = (const float*)d_in[8];
  const float* uw      = (const float*)d_in[9];
  const float* ub      = (const float*)d_in[10];
  const float* hw      = (const float*)d_in[11];
  const float* hb      = (const float*)d_in[12];
  float* ws  = (float*)d_ws;
  float* out = (float*)d_out;

  hipLaunchKernelGGL(init_kernel, dim3(64), dim3(256), 0, stream, ws);
  hipLaunchKernelGGL(transpose_kernel, dim3(1600, 4), dim3(256), 0, stream, session, ws);
  hipLaunchKernelGGL(vt_kernel, dim3(256), dim3(256), 0, stream, w, target, ws);
  hipLaunchKernelGGL(gru_kernel, dim3(256), dim3(256), 0, stream,
                     wih, whh, bih, bhh, ws);
  hipLaunchKernelGGL(attn1_kernel, dim3(200), dim3(256), 0, stream, ws);
  hipLaunchKernelGGL(attn2_kernel, dim3(256), dim3(256), 0, stream, ws);
  hipLaunchKernelGGL(augru_kernel, dim3(256), dim3(256), 0, stream,
                     rw, rb, uw, ub, hw, hb, ws, out);
}

// Round 4
// 20401.390 us; speedup vs baseline: 2.1678x; 2.1678x over previous
//
#include <hip/hip_runtime.h>
#include <math.h>

#define NB 256
#define NL 200
#define ND 512
#define SLICE 131072ul  // 512 k * 256 b floats

// ---- workspace layout (float offsets), all [k][b] transposed ----
// BIG[201][512][256]: slice u+1 = sessionT[u]; GRU writes h_t = sseqT[t] at slice t.
#define BIG_OFF   0ul
#define LG_OFF    26345472ul   // logits [200][256]
#define ATT_OFF   26396672ul   // att    [200][256]
#define VT_OFF    26447872ul   // vtT    [512][256]
#define HBUF_OFF  26578944ul   // AUGRU h ping-pong [2][512][256]
#define HR_OFF    26841088ul   // r*h [512][256]
#define FLAGS_OFF 26972160ul   // 768 u32 epoch flags: gf[2][128], af1[2][128], af2[2][128]

__device__ __forceinline__ float sigmoidf_(float x) { return 1.0f / (1.0f + expf(-x)); }

// ---- coherent (LLC-direct, fence-free) accessors: relaxed agent atomics ----
__device__ __forceinline__ float2 cohld2(const float* p) {
  union { double d; float2 f; } u;
  u.d = __hip_atomic_load((const double*)p, __ATOMIC_RELAXED, __HIP_MEMORY_SCOPE_AGENT);
  return u.f;
}
__device__ __forceinline__ void cohst2(float* p, float2 v) {
  union { double d; float2 f; } u;
  u.f = v;
  __hip_atomic_store((double*)p, u.d, __ATOMIC_RELAXED, __HIP_MEMORY_SCOPE_AGENT);
}

// ---- grid barrier: NO fences (no L2 sweeps). Data stores are sc1 write-through;
// drain them (vmcnt) in every thread, sync, then one relaxed flag store. ----
__device__ __forceinline__ void bar_arrive(unsigned* f, int slot, unsigned val) {
  asm volatile("s_waitcnt vmcnt(0)" ::: "memory");
  __syncthreads();
  if (threadIdx.x == 0) {
    __hip_atomic_store(f + slot, val, __ATOMIC_RELAXED, __HIP_MEMORY_SCOPE_AGENT);
  }
}
__device__ __forceinline__ void bar_wait(const unsigned* f, unsigned val) {
  if (threadIdx.x < 128) {
    int guard = 0;
    while (__hip_atomic_load(f + threadIdx.x, __ATOMIC_RELAXED, __HIP_MEMORY_SCOPE_AGENT) < val) {
      if (++guard > (1 << 16)) break;  // deadlock escape: terminate, don't hang
    }
  }
  __syncthreads();
}

// ---- init: zero flags (graph replays => must rerun every call) ----
__global__ void init_kernel(float* __restrict__ ws) {
  unsigned* const fl = (unsigned*)(ws + FLAGS_OFF);
  for (int j = threadIdx.x; j < 768; j += 256) fl[j] = 0u;
}

// ---- transpose session [256][102400] -> BIG slices 1..200 as [tk][b] ----
__global__ __launch_bounds__(256) void transpose_kernel(const float* __restrict__ in,
                                                        float* __restrict__ ws) {
  __shared__ float tile[64][65];
  const int tx = threadIdx.x & 63, ty = threadIdx.x >> 6;
  const size_t tk0 = (size_t)blockIdx.x * 64;
  const int b0 = blockIdx.y * 64;
#pragma unroll
  for (int r = 0; r < 16; ++r) {
    const int bb = ty + 4 * r;
    tile[bb][tx] = in[(size_t)(b0 + bb) * 102400 + tk0 + tx];
  }
  __syncthreads();
  float* const big1 = ws + BIG_OFF + SLICE;  // slice 1 = sessionT[0]
#pragma unroll
  for (int r = 0; r < 16; ++r) {
    const int kk = ty + 4 * r;
    big1[(tk0 + kk) * 256 + b0 + tx] = tile[tx][kk];
  }
}

// ---- vtT[d][b] = sum_e w[d,e] * target[b,e] ----
__global__ __launch_bounds__(256) void vt_kernel(const float* __restrict__ w,
                                                 const float* __restrict__ tgt,
                                                 float* __restrict__ ws) {
  __shared__ float t_s[512];
  const int b = blockIdx.x, tid = threadIdx.x;
  for (int i = tid; i < 512; i += 256) t_s[i] = tgt[(size_t)b * 512 + i];
  __syncthreads();
  const int wv = tid >> 6, lane = tid & 63;
  for (int d = wv; d < 512; d += 4) {
    const float* const wr = w + (size_t)d * 512;
    const float4 a  = *(const float4*)(wr + lane * 8);
    const float4 a2 = *(const float4*)(wr + lane * 8 + 4);
    float s = a.x * t_s[lane * 8 + 0] + a.y * t_s[lane * 8 + 1] +
              a.z * t_s[lane * 8 + 2] + a.w * t_s[lane * 8 + 3] +
              a2.x * t_s[lane * 8 + 4] + a2.y * t_s[lane * 8 + 5] +
              a2.z * t_s[lane * 8 + 6] + a2.w * t_s[lane * 8 + 7];
    for (int off = 32; off > 0; off >>= 1) s += __shfl_xor(s, off);
    if (lane == 0) ws[VT_OFF + (size_t)d * 256 + b] = s;
  }
}

// ---- persistent GRU: 2 halves x 128 col-groups; h lives in BIG slices ----
__global__ __launch_bounds__(256) void gru_kernel(const float* __restrict__ wih,
                                                  const float* __restrict__ whh,
                                                  const float* __restrict__ bih,
                                                  const float* __restrict__ bhh,
                                                  float* __restrict__ ws) {
  __shared__ float wih_s[12 * 512];  // slot cc: gate=cc>>2, q=cc&3 -> row gate*512+c0+q
  __shared__ float whh_s[12 * 512];
  __shared__ float xp_s[12 * 128];
  __shared__ float hp_s[12 * 128];
  __shared__ float bih_s[12], bhh_s[12];

  const int bg = blockIdx.x >> 7;
  const int ng = blockIdx.x & 127;
  const int b0 = bg << 7;
  const int c0 = ng << 2;
  const int tid = threadIdx.x;

  for (int i = tid; i < 12 * 512; i += 256) {
    const int cc = i >> 9, kk = i & 511;
    const int grow = ((cc >> 2) << 9) + c0 + (cc & 3);
    wih_s[i] = wih[(size_t)grow * 512 + kk];
    whh_s[i] = whh[(size_t)grow * 512 + kk];
  }
  if (tid < 12) {
    const int grow = ((tid >> 2) << 9) + c0 + (tid & 3);
    bih_s[tid] = bih[grow];
    bhh_s[tid] = bhh[grow];
  }
  __syncthreads();

  float* const big = ws + BIG_OFF;
  unsigned* const gf = (unsigned*)(ws + FLAGS_OFF) + (bg << 7);

  const int l = tid & 63;
  const int wv = tid >> 6;
  const int cb = wv * 3;            // this wave's 3 LDS col slots
  const int boff = b0 + 2 * l;      // rows 2l, 2l+1 via float2
  const float* const w0x = wih_s + (size_t)(cb + 0) * 512;
  const float* const w1x = wih_s + (size_t)(cb + 1) * 512;
  const float* const w2x = wih_s + (size_t)(cb + 2) * 512;
  const float* const w0h = whh_s + (size_t)(cb + 0) * 512;
  const float* const w1h = whh_s + (size_t)(cb + 1) * 512;
  const float* const w2h = whh_s + (size_t)(cb + 2) * 512;

  // gate-stage mapping: col q, rows 2*b2, 2*b2+1
  const int gq = tid >> 6, b2 = tid & 63;
  const size_t go = (size_t)(c0 + gq) * 256 + b0 + 2 * b2;

  for (int t = 0; t < NL; ++t) {
    // x-dot: sessionT[t] = slice t+1, sc1 loads (no L2 pollution), pre-barrier
    const float* const xp = big + (size_t)(t + 1) * SLICE + boff;
    float a00 = 0, a01 = 0, a10 = 0, a11 = 0, a20 = 0, a21 = 0;
    for (int g = 0; g < 32; ++g) {
      const int kb = g * 16;
      float2 xv[16];
#pragma unroll
      for (int j = 0; j < 16; ++j) xv[j] = cohld2(xp + (size_t)(kb + j) * 256);
#pragma unroll
      for (int j = 0; j < 16; ++j) {
        const int k = kb + j;
        const float u0 = w0x[k], u1 = w1x[k], u2 = w2x[k];
        a00 += xv[j].x * u0; a01 += xv[j].y * u0;
        a10 += xv[j].x * u1; a11 += xv[j].y * u1;
        a20 += xv[j].x * u2; a21 += xv[j].y * u2;
      }
    }
    if (t > 0) bar_wait(gf, (unsigned)t);
    float h00 = 0, h01 = 0, h10 = 0, h11 = 0, h20 = 0, h21 = 0;
    if (t > 0) {
      // h-dot: h_{t-1} = slice t-1, NORMAL loads (fresh addresses, L2-shared)
      const float* const hp = big + (size_t)(t - 1) * SLICE + boff;
#pragma unroll 8
      for (int k = 0; k < 512; ++k) {
        const float2 hv = *(const float2*)(hp + (size_t)k * 256);
        const float u0 = w0h[k], u1 = w1h[k], u2 = w2h[k];
        h00 += hv.x * u0; h01 += hv.y * u0;
        h10 += hv.x * u1; h11 += hv.y * u1;
        h20 += hv.x * u2; h21 += hv.y * u2;
      }
    }
    *(float2*)(xp_s + (size_t)(cb + 0) * 128 + 2 * l) = make_float2(a00, a01);
    *(float2*)(xp_s + (size_t)(cb + 1) * 128 + 2 * l) = make_float2(a10, a11);
    *(float2*)(xp_s + (size_t)(cb + 2) * 128 + 2 * l) = make_float2(a20, a21);
    *(float2*)(hp_s + (size_t)(cb + 0) * 128 + 2 * l) = make_float2(h00, h01);
    *(float2*)(hp_s + (size_t)(cb + 1) * 128 + 2 * l) = make_float2(h10, h11);
    *(float2*)(hp_s + (size_t)(cb + 2) * 128 + 2 * l) = make_float2(h20, h21);
    __syncthreads();

    // gates for (col gq, rows 2b2, 2b2+1); h_t stored to BIG slice t (sc1)
    {
      float2 hprev = make_float2(0.0f, 0.0f);
      if (t > 0) hprev = *(const float2*)(big + (size_t)(t - 1) * SLICE + go);
      float hn2[2];
#pragma unroll
      for (int e = 0; e < 2; ++e) {
        const int row = 2 * b2 + e;
        const float xr = xp_s[(size_t)(0 + gq) * 128 + row] + bih_s[0 + gq];
        const float hr = hp_s[(size_t)(0 + gq) * 128 + row] + bhh_s[0 + gq];
        const float xz = xp_s[(size_t)(4 + gq) * 128 + row] + bih_s[4 + gq];
        const float hz = hp_s[(size_t)(4 + gq) * 128 + row] + bhh_s[4 + gq];
        const float xn = xp_s[(size_t)(8 + gq) * 128 + row] + bih_s[8 + gq];
        const float hn = hp_s[(size_t)(8 + gq) * 128 + row] + bhh_s[8 + gq];
        const float r = sigmoidf_(xr + hr);
        const float z = sigmoidf_(xz + hz);
        const float n = tanhf(xn + r * hn);
        const float hp0 = (e == 0) ? hprev.x : hprev.y;
        hn2[e] = (1.0f - z) * n + z * hp0;
      }
      cohst2(big + (size_t)t * SLICE + go, make_float2(hn2[0], hn2[1]));
    }
    __syncthreads();  // LDS reuse guard before next step overwrites xp_s/hp_s
    bar_arrive(gf, ng, (unsigned)(t + 1));
  }
}

// ---- attn1: logits[l][b] = sum_k sseqT[l][k][b] * vtT[k][b] ----
__global__ __launch_bounds__(256) void attn1_kernel(float* __restrict__ ws) {
  const int l = blockIdx.x, tid = threadIdx.x;
  const float* const sl = ws + BIG_OFF + (size_t)l * SLICE + tid;
  const float* const vtt = ws + VT_OFF + tid;
  float acc = 0.0f;
#pragma unroll 8
  for (int k = 0; k < 512; ++k)
    acc += sl[(size_t)k * 256] * vtt[(size_t)k * 256];
  ws[LG_OFF + (size_t)l * 256 + tid] = acc;
}

// ---- attn2: softmax over l per batch row; write attT[l][b] ----
__global__ __launch_bounds__(256) void attn2_kernel(float* __restrict__ ws) {
  __shared__ float red[8];
  const int b = blockIdx.x, tid = threadIdx.x;
  const float v = (tid < NL) ? ws[LG_OFF + (size_t)tid * 256 + b] : -3.0e38f;
  float m = v;
  for (int off = 32; off > 0; off >>= 1) m = fmaxf(m, __shfl_xor(m, off));
  if ((tid & 63) == 0) red[tid >> 6] = m;
  __syncthreads();
  m = fmaxf(fmaxf(red[0], red[1]), fmaxf(red[2], red[3]));
  const float e = (tid < NL) ? expf(v - m) : 0.0f;
  float s = e;
  for (int off = 32; off > 0; off >>= 1) s += __shfl_xor(s, off);
  __syncthreads();
  if ((tid & 63) == 0) red[4 + (tid >> 6)] = s;
  __syncthreads();
  s = red[4] + red[5] + red[6] + red[7];
  if (tid < NL) ws[ATT_OFF + (size_t)tid * 256 + b] = e / s;
}

// ---- persistent AUGRU: x normal/L2; h, r*h via sc1 atomics; fence-free bars ----
__global__ __launch_bounds__(256) void augru_kernel(const float* __restrict__ rw,
                                                    const float* __restrict__ rbias,
                                                    const float* __restrict__ uw,
                                                    const float* __restrict__ ubias,
                                                    const float* __restrict__ hw,
                                                    const float* __restrict__ hbias,
                                                    float* __restrict__ ws,
                                                    float* __restrict__ out) {
  __shared__ float wr_s[4 * 1024];
  __shared__ float wu_s[4 * 1024];
  __shared__ float wh_s[4 * 1024];
  __shared__ float rbs[4], ubs[4], hbs[4];

  const int bg = blockIdx.x >> 7, ng = blockIdx.x & 127;
  const int b0 = bg << 7, c0 = ng << 2;
  const int tid = threadIdx.x;
  for (int i = tid; i < 4 * 1024; i += 256) {
    const int q = i >> 10, kk = i & 1023;
    wr_s[i] = rw[(size_t)(c0 + q) * 1024 + kk];
    wu_s[i] = uw[(size_t)(c0 + q) * 1024 + kk];
    wh_s[i] = hw[(size_t)(c0 + q) * 1024 + kk];
  }
  if (tid < 4) {
    rbs[tid] = rbias[c0 + tid];
    ubs[tid] = ubias[c0 + tid];
    hbs[tid] = hbias[c0 + tid];
  }
  __syncthreads();

  float* const big = ws + BIG_OFF;
  float* const hbuf = ws + HBUF_OFF;
  float* const hrg = ws + HR_OFF;
  const float* const att = ws + ATT_OFF;
  unsigned* const fbase = (unsigned*)(ws + FLAGS_OFF);
  unsigned* const af1 = fbase + 256 + (bg << 7);
  unsigned* const af2 = fbase + 512 + (bg << 7);

  const int l = tid & 63, q = tid >> 6;   // rows 2l,2l+1; col q
  const int boff = b0 + 2 * l;
  const float* const wrq = wr_s + ((size_t)q << 10);
  const float* const wuq = wu_s + ((size_t)q << 10);
  const float* const whq = wh_s + ((size_t)q << 10);
  const size_t o = (size_t)(c0 + q) * 256 + boff;

  for (int t = 0; t < NL; ++t) {
    const float* const xp = big + (size_t)t * SLICE + boff;  // sseqT[t], normal/L2
    // phase1 x-halves before the wait
    float pr0 = 0, pr1 = 0, pu0 = 0, pu1 = 0;
#pragma unroll 8
    for (int k = 0; k < 512; ++k) {
      const float2 xv = *(const float2*)(xp + (size_t)k * 256);
      const float ur = wrq[512 + k], uu = wuq[512 + k];
      pr0 += xv.x * ur; pr1 += xv.y * ur;
      pu0 += xv.x * uu; pu1 += xv.y * uu;
    }
    if (t > 0) bar_wait(af2, (unsigned)t);
    // h source: t=0 -> GRU final (BIG slice 199); else ping-pong (sc1)
    const float* const hbase = (t == 0) ? (big + 199ul * SLICE)
                                        : (hbuf + (size_t)(t & 1) * SLICE);
    {
      const float* const hp = hbase + boff;
      for (int g = 0; g < 32; ++g) {
        const int kb = g * 16;
        float2 hv[16];
#pragma unroll
        for (int j = 0; j < 16; ++j) hv[j] = cohld2(hp + (size_t)(kb + j) * 256);
#pragma unroll
        for (int j = 0; j < 16; ++j) {
          const float ur = wrq[kb + j], uu = wuq[kb + j];
          pr0 += hv[j].x * ur; pr1 += hv[j].y * ur;
          pu0 += hv[j].x * uu; pu1 += hv[j].y * uu;
        }
      }
    }
    const float rg0 = sigmoidf_(pr0 + rbs[q]);
    const float rg1 = sigmoidf_(pr1 + rbs[q]);
    const float ug0 = sigmoidf_(pu0 + ubs[q]);  // kept in regs for phase2
    const float ug1 = sigmoidf_(pu1 + ubs[q]);
    const float2 hcur = cohld2(hbase + o);
    cohst2(hrg + o, make_float2(rg0 * hcur.x, rg1 * hcur.y));
    bar_arrive(af1, ng, (unsigned)(t + 1));

    // phase2 x-halves before the wait on r*h (L2-warm from phase1)
    float ph0 = 0, ph1 = 0;
#pragma unroll 8
    for (int k = 0; k < 512; ++k) {
      const float2 xv = *(const float2*)(xp + (size_t)k * 256);
      const float uh = whq[512 + k];
      ph0 += xv.x * uh; ph1 += xv.y * uh;
    }
    bar_wait(af1, (unsigned)(t + 1));
    {
      const float* const hrp = hrg + boff;
      for (int g = 0; g < 32; ++g) {
        const int kb = g * 16;
        float2 rv[16];
#pragma unroll
        for (int j = 0; j < 16; ++j) rv[j] = cohld2(hrp + (size_t)(kb + j) * 256);
#pragma unroll
        for (int j = 0; j < 16; ++j) {
          const float uh = whq[kb + j];
          ph0 += rv[j].x * uh; ph1 += rv[j].y * uh;
        }
      }
    }
    const float hh0 = tanhf(ph0 + hbs[q]);
    const float hh1 = tanhf(ph1 + hbs[q]);
    const float2 av = *(const float2*)(att + (size_t)t * 256 + boff);
    const float u0 = av.x * ug0, u1 = av.y * ug1;
    const float hn0 = (1.0f - u0) * hcur.x + u0 * hh0;
    const float hn1 = (1.0f - u1) * hcur.y + u1 * hh1;
    if (t == NL - 1) {
      out[(size_t)boff * 512 + c0 + q] = hn0;
      out[(size_t)(boff + 1) * 512 + c0 + q] = hn1;
    } else {
      cohst2(hbuf + (size_t)((t + 1) & 1) * SLICE + o, make_float2(hn0, hn1));
    }
    bar_arrive(af2, ng, (unsigned)(t + 1));
  }
}

extern "C" void kernel_launch(void* const* d_in, const int* in_sizes, int n_in,
                              void* d_out, int out_size, void* d_ws, size_t ws_size,
                              hipStream_t stream) {
  (void)in_sizes; (void)n_in; (void)out_size; (void)ws_size;
  const float* session = (const float*)d_in[0];
  const float* target  = (const float*)d_in[1];
  const float* w       = (const float*)d_in[2];
  const float* wih     = (const float*)d_in[3];
  const float* whh     = (const float*)d_in[4];
  const float* bih     = (const float*)d_in[5];
  const float* bhh     = (const float*)d_in[6];
  const float* rw      = (const float*)d_in[7];
  const float* rb      = (const float*)d_in[8];
  const float* uw      = (const float*)d_in[9];
  const float* ub      = (const float*)d_in[10];
  const float* hw      = (const float*)d_in[11];
  const float* hb      = (const float*)d_in[12];
  float* ws  = (float*)d_ws;
  float* out = (float*)d_out;

  hipLaunchKernelGGL(init_kernel, dim3(1), dim3(256), 0, stream, ws);
  hipLaunchKernelGGL(transpose_kernel, dim3(1600, 4), dim3(256), 0, stream, session, ws);
  hipLaunchKernelGGL(vt_kernel, dim3(256), dim3(256), 0, stream, w, target, ws);
  hipLaunchKernelGGL(gru_kernel, dim3(256), dim3(256), 0, stream,
                     wih, whh, bih, bhh, ws);
  hipLaunchKernelGGL(attn1_kernel, dim3(200), dim3(256), 0, stream, ws);
  hipLaunchKernelGGL(attn2_kernel, dim3(256), dim3(256), 0, stream, ws);
  hipLaunchKernelGGL(augru_kernel, dim3(256), dim3(256), 0, stream,
                     rw, rb, uw, ub, hw, hb, ws, out);
}

// Round 5
// 17993.056 us; speedup vs baseline: 2.4579x; 1.1338x over previous
//
#include <hip/hip_runtime.h>
#include <math.h>

#define NL 200
#define SLICE 131072ul  // 512 k * 256 b floats

// ---- workspace layout (float offsets), activations stored [k][b] ----
// BIG[201][512][256]: slice u+1 = sessionT[u]; GRU writes h_t = sseqT[t] at slice t.
#define BIG_OFF   0ul
#define LG_OFF    26345472ul   // logits [200][256]
#define ATT_OFF   26396672ul   // att    [200][256]
#define VT_OFF    26447872ul   // vtT    [512][256]
#define HBUF_OFF  26578944ul   // AUGRU h ping-pong [2][512][256]
#define HR_OFF    26841088ul   // r*h [512][256]
#define FLAGS_OFF 26972160ul   // 768 u32 epoch flags: gf[2][128], af1[2][128], af2[2][128]

__device__ __forceinline__ float sigmoidf_(float x) { return 1.0f / (1.0f + expf(-x)); }

// ---- LLC-direct (sc1) accessors: relaxed agent atomics, no fences ----
__device__ __forceinline__ float2 cohld2(const float* p) {
  union { double d; float2 f; } u;
  u.d = __hip_atomic_load((const double*)p, __ATOMIC_RELAXED, __HIP_MEMORY_SCOPE_AGENT);
  return u.f;
}
__device__ __forceinline__ void cohst2(float* p, float2 v) {
  union { double d; float2 f; } u;
  u.f = v;
  __hip_atomic_store((double*)p, u.d, __ATOMIC_RELAXED, __HIP_MEMORY_SCOPE_AGENT);
}
__device__ __forceinline__ void cohst1(float* p, float v) {
  __hip_atomic_store(p, v, __ATOMIC_RELAXED, __HIP_MEMORY_SCOPE_AGENT);
}

// ---- grid wait: one wave checks all 128 flags (lane i -> i, i+64) ----
__device__ __forceinline__ void gwait(const unsigned* f, unsigned val) {
  const int i = threadIdx.x & 63;
  bool d0 = false, d1 = false;
  int guard = 0;
  for (;;) {
    if (!d0) d0 = __hip_atomic_load(f + i, __ATOMIC_RELAXED, __HIP_MEMORY_SCOPE_AGENT) >= val;
    if (!d1) d1 = __hip_atomic_load(f + i + 64, __ATOMIC_RELAXED, __HIP_MEMORY_SCOPE_AGENT) >= val;
    if (__all(d0 && d1)) break;
    if (++guard > (1 << 22)) break;  // deadlock escape: terminate, don't hang
  }
  asm volatile("" ::: "memory");
}

// ---- LDS producer/consumer helpers (workgroup scope, no cache ops) ----
__device__ __forceinline__ void lds_wait(unsigned* c, unsigned val) {
  int guard = 0;
  while (__hip_atomic_load(c, __ATOMIC_RELAXED, __HIP_MEMORY_SCOPE_WORKGROUP) < val) {
    if (++guard > (1 << 25)) break;
  }
  asm volatile("" ::: "memory");
}
__device__ __forceinline__ void lds_sig(unsigned* c) {
  asm volatile("s_waitcnt lgkmcnt(0)" ::: "memory");  // prior ds ops done
  if ((threadIdx.x & 63) == 0)
    __hip_atomic_fetch_add(c, 1u, __ATOMIC_RELAXED, __HIP_MEMORY_SCOPE_WORKGROUP);
}

// ---- init: zero flags (graph replays => rerun every call) ----
__global__ void init_kernel(float* __restrict__ ws) {
  unsigned* const fl = (unsigned*)(ws + FLAGS_OFF);
  for (int j = threadIdx.x; j < 768; j += 256) fl[j] = 0u;
}

// ---- transpose session -> BIG slices 1..200 as [k][b]; sc1 stores so no
// L2 copy of these lines ever predates the GRU's sc1 h-overwrite ----
__global__ __launch_bounds__(256) void transpose_kernel(const float* __restrict__ in,
                                                        float* __restrict__ ws) {
  __shared__ float tile[64][65];
  const int tx = threadIdx.x & 63, ty = threadIdx.x >> 6;
  const size_t tk0 = (size_t)blockIdx.x * 64;
  const int b0 = blockIdx.y * 64;
#pragma unroll
  for (int r = 0; r < 16; ++r) {
    const int bb = ty + 4 * r;
    tile[bb][tx] = in[(size_t)(b0 + bb) * 102400 + tk0 + tx];
  }
  __syncthreads();
  float* const big1 = ws + BIG_OFF + SLICE;
#pragma unroll
  for (int r = 0; r < 16; ++r) {
    const int kk = ty + 4 * r;
    cohst1(big1 + (tk0 + kk) * 256 + b0 + tx, tile[tx][kk]);
  }
}

// ---- vtT[d][b] = sum_e w[d,e] * target[b,e] ----
__global__ __launch_bounds__(256) void vt_kernel(const float* __restrict__ w,
                                                 const float* __restrict__ tgt,
                                                 float* __restrict__ ws) {
  __shared__ float t_s[512];
  const int b = blockIdx.x, tid = threadIdx.x;
  for (int i = tid; i < 512; i += 256) t_s[i] = tgt[(size_t)b * 512 + i];
  __syncthreads();
  const int wv = tid >> 6, lane = tid & 63;
  for (int d = wv; d < 512; d += 4) {
    const float* const wr = w + (size_t)d * 512;
    const float4 a  = *(const float4*)(wr + lane * 8);
    const float4 a2 = *(const float4*)(wr + lane * 8 + 4);
    float s = a.x * t_s[lane * 8 + 0] + a.y * t_s[lane * 8 + 1] +
              a.z * t_s[lane * 8 + 2] + a.w * t_s[lane * 8 + 3] +
              a2.x * t_s[lane * 8 + 4] + a2.y * t_s[lane * 8 + 5] +
              a2.z * t_s[lane * 8 + 6] + a2.w * t_s[lane * 8 + 7];
    for (int off = 32; off > 0; off >>= 1) s += __shfl_xor(s, off);
    if (lane == 0) ws[VT_OFF + (size_t)d * 256 + b] = s;
  }
}

// ---- persistent GRU: 512 thr = 4 x-waves (run-ahead xproj) + 4 h-waves ----
__global__ __launch_bounds__(512) void gru_kernel(const float* __restrict__ wih,
                                                  const float* __restrict__ whh,
                                                  const float* __restrict__ bih,
                                                  const float* __restrict__ bhh,
                                                  float* __restrict__ ws) {
  __shared__ float wih_s[12 * 512];   // slot g*4+q : gate g, col c0+q
  __shared__ float whh_s[12 * 512];
  __shared__ float xb[4][12][128];    // 4-deep x-projection ring
  __shared__ float bih_s[12], bhh_s[12];
  __shared__ unsigned xdone, xcons, hcnt, gok;

  const int bg = blockIdx.x >> 7;
  const int ng = blockIdx.x & 127;
  const int b0 = bg << 7;
  const int c0 = ng << 2;
  const int tid = threadIdx.x;

  for (int i = tid; i < 12 * 512; i += 512) {
    const int cc = i >> 9, kk = i & 511;
    const int grow = ((cc >> 2) << 9) + c0 + (cc & 3);
    wih_s[i] = wih[(size_t)grow * 512 + kk];
    whh_s[i] = whh[(size_t)grow * 512 + kk];
  }
  if (tid < 12) {
    const int grow = ((tid >> 2) << 9) + c0 + (tid & 3);
    bih_s[tid] = bih[grow];
    bhh_s[tid] = bhh[grow];
  }
  if (tid == 0) { xdone = 0u; xcons = 0u; hcnt = 0u; gok = 0u; }
  __syncthreads();  // ONLY full-block sync; waves diverge below

  float* const big = ws + BIG_OFF;
  unsigned* const gf = (unsigned*)(ws + FLAGS_OFF) + (bg << 7);

  const int wv = tid >> 6;
  const int l = tid & 63;
  const int q = wv & 3;
  const int boff = b0 + 2 * l;

  if (wv < 4) {
    // ---- x-waves: xproj[t] for col c0+q, rows 2l,2l+1, gates r,z,n ----
    const float* const w0 = wih_s + (size_t)(0 + q) * 512;
    const float* const w1 = wih_s + (size_t)(4 + q) * 512;
    const float* const w2 = wih_s + (size_t)(8 + q) * 512;
    for (int u = 0; u < NL; ++u) {
      if (u >= 4) lds_wait(&xcons, 4u * (unsigned)(u - 3));
      const float* const xp = big + (size_t)(u + 1) * SLICE + boff;
      float a00 = 0, a01 = 0, a10 = 0, a11 = 0, a20 = 0, a21 = 0;
      for (int gg = 0; gg < 16; ++gg) {
        float2 v[32];
#pragma unroll
        for (int j = 0; j < 32; ++j) v[j] = cohld2(xp + (size_t)(gg * 32 + j) * 256);
#pragma unroll
        for (int j = 0; j < 32; ++j) {
          const int k = gg * 32 + j;
          const float u0 = w0[k], u1 = w1[k], u2 = w2[k];
          a00 += v[j].x * u0; a01 += v[j].y * u0;
          a10 += v[j].x * u1; a11 += v[j].y * u1;
          a20 += v[j].x * u2; a21 += v[j].y * u2;
        }
      }
      float* const xo = &xb[u & 3][0][0];
      *(float2*)(xo + (0 + q) * 128 + 2 * l) = make_float2(a00, a01);
      *(float2*)(xo + (4 + q) * 128 + 2 * l) = make_float2(a10, a11);
      *(float2*)(xo + (8 + q) * 128 + 2 * l) = make_float2(a20, a21);
      lds_sig(&xdone);
    }
  } else {
    // ---- h-waves: recurrence critical path ----
    const float* const w0 = whh_s + (size_t)(0 + q) * 512;
    const float* const w1 = whh_s + (size_t)(4 + q) * 512;
    const float* const w2 = whh_s + (size_t)(8 + q) * 512;
    const size_t o = (size_t)(c0 + q) * 256 + boff;
    for (int t = 0; t < NL; ++t) {
      if (t > 0) {
        if (wv == 4) {
          gwait(gf, (unsigned)t);
          if (l == 0)
            __hip_atomic_store(&gok, (unsigned)t, __ATOMIC_RELAXED, __HIP_MEMORY_SCOPE_WORKGROUP);
        } else {
          lds_wait(&gok, (unsigned)t);
        }
      }
      float h00 = 0, h01 = 0, h10 = 0, h11 = 0, h20 = 0, h21 = 0;
      float2 hprev = make_float2(0.0f, 0.0f);
      if (t > 0) {
        // h_{t-1} = BIG slice t-1. Normal loads: provably never stale
        // (these addrs were only ever sc1-written/sc1-read before).
        const float* const hp = big + (size_t)(t - 1) * SLICE + boff;
        for (int gg = 0; gg < 16; ++gg) {
          float2 v[32];
#pragma unroll
          for (int j = 0; j < 32; ++j) v[j] = *(const float2*)(hp + (size_t)(gg * 32 + j) * 256);
#pragma unroll
          for (int j = 0; j < 32; ++j) {
            const int k = gg * 32 + j;
            const float u0 = w0[k], u1 = w1[k], u2 = w2[k];
            h00 += v[j].x * u0; h01 += v[j].y * u0;
            h10 += v[j].x * u1; h11 += v[j].y * u1;
            h20 += v[j].x * u2; h21 += v[j].y * u2;
          }
        }
        hprev = *(const float2*)(big + (size_t)(t - 1) * SLICE + o);
      }
      lds_wait(&xdone, 4u * (unsigned)(t + 1));
      const float* const xo = &xb[t & 3][0][0];
      const float2 xr = *(const float2*)(xo + (0 + q) * 128 + 2 * l);
      const float2 xz = *(const float2*)(xo + (4 + q) * 128 + 2 * l);
      const float2 xn = *(const float2*)(xo + (8 + q) * 128 + 2 * l);
      lds_sig(&xcons);
      const float r0 = sigmoidf_(xr.x + bih_s[0 + q] + h00 + bhh_s[0 + q]);
      const float r1 = sigmoidf_(xr.y + bih_s[0 + q] + h01 + bhh_s[0 + q]);
      const float z0 = sigmoidf_(xz.x + bih_s[4 + q] + h10 + bhh_s[4 + q]);
      const float z1 = sigmoidf_(xz.y + bih_s[4 + q] + h11 + bhh_s[4 + q]);
      const float n0 = tanhf(xn.x + bih_s[8 + q] + r0 * (h20 + bhh_s[8 + q]));
      const float n1 = tanhf(xn.y + bih_s[8 + q] + r1 * (h21 + bhh_s[8 + q]));
      const float hn0 = (1.0f - z0) * n0 + z0 * hprev.x;
      const float hn1 = (1.0f - z1) * n1 + z1 * hprev.y;
      cohst2(big + (size_t)t * SLICE + o, make_float2(hn0, hn1));
      asm volatile("s_waitcnt vmcnt(0)" ::: "memory");
      if (l == 0)
        __hip_atomic_fetch_add(&hcnt, 1u, __ATOMIC_RELAXED, __HIP_MEMORY_SCOPE_WORKGROUP);
      if (wv == 4 && l == 0) {
        int guard = 0;
        while (__hip_atomic_load(&hcnt, __ATOMIC_RELAXED, __HIP_MEMORY_SCOPE_WORKGROUP)
               < 4u * (unsigned)(t + 1)) {
          if (++guard > (1 << 25)) break;
        }
        __hip_atomic_store(gf + ng, (unsigned)(t + 1), __ATOMIC_RELAXED, __HIP_MEMORY_SCOPE_AGENT);
      }
    }
  }
}

// ---- attn1: logits[l][b] = sum_k sseqT[l][k][b] * vtT[k][b] ----
__global__ __launch_bounds__(256) void attn1_kernel(float* __restrict__ ws) {
  const int l = blockIdx.x, tid = threadIdx.x;
  const float* const sl = ws + BIG_OFF + (size_t)l * SLICE + tid;
  const float* const vtt = ws + VT_OFF + tid;
  float acc = 0.0f;
#pragma unroll 8
  for (int k = 0; k < 512; ++k)
    acc += sl[(size_t)k * 256] * vtt[(size_t)k * 256];
  ws[LG_OFF + (size_t)l * 256 + tid] = acc;
}

// ---- attn2: softmax over l per batch row; write attT[l][b] ----
__global__ __launch_bounds__(256) void attn2_kernel(float* __restrict__ ws) {
  __shared__ float red[8];
  const int b = blockIdx.x, tid = threadIdx.x;
  const float v = (tid < NL) ? ws[LG_OFF + (size_t)tid * 256 + b] : -3.0e38f;
  float m = v;
  for (int off = 32; off > 0; off >>= 1) m = fmaxf(m, __shfl_xor(m, off));
  if ((tid & 63) == 0) red[tid >> 6] = m;
  __syncthreads();
  m = fmaxf(fmaxf(red[0], red[1]), fmaxf(red[2], red[3]));
  const float e = (tid < NL) ? expf(v - m) : 0.0f;
  float s = e;
  for (int off = 32; off > 0; off >>= 1) s += __shfl_xor(s, off);
  __syncthreads();
  if ((tid & 63) == 0) red[4 + (tid >> 6)] = s;
  __syncthreads();
  s = red[4] + red[5] + red[6] + red[7];
  if (tid < NL) ws[ATT_OFF + (size_t)tid * 256 + b] = e / s;
}

// ---- persistent AUGRU: 4 x-waves (all 3 x-projections, one x pass) + 4 h-waves ----
__global__ __launch_bounds__(512) void augru_kernel(const float* __restrict__ rw,
                                                    const float* __restrict__ rbias,
                                                    const float* __restrict__ uw,
                                                    const float* __restrict__ ubias,
                                                    const float* __restrict__ hw,
                                                    const float* __restrict__ hbias,
                                                    float* __restrict__ ws,
                                                    float* __restrict__ out) {
  __shared__ float wr_s[4 * 1024];
  __shared__ float wu_s[4 * 1024];
  __shared__ float wh_s[4 * 1024];
  __shared__ float xbuf[4][3][4][128];  // [ring][mat r,u,h][col][row]
  __shared__ float rbs[4], ubs[4], hbs[4];
  __shared__ unsigned xdone, xcons, hcnt1, hcnt2, gok1, gok2;

  const int bg = blockIdx.x >> 7, ng = blockIdx.x & 127;
  const int b0 = bg << 7, c0 = ng << 2;
  const int tid = threadIdx.x;
  for (int i = tid; i < 4 * 1024; i += 512) {
    const int qq = i >> 10, kk = i & 1023;
    wr_s[i] = rw[(size_t)(c0 + qq) * 1024 + kk];
    wu_s[i] = uw[(size_t)(c0 + qq) * 1024 + kk];
    wh_s[i] = hw[(size_t)(c0 + qq) * 1024 + kk];
  }
  if (tid < 4) {
    rbs[tid] = rbias[c0 + tid];
    ubs[tid] = ubias[c0 + tid];
    hbs[tid] = hbias[c0 + tid];
  }
  if (tid == 0) { xdone = 0u; xcons = 0u; hcnt1 = 0u; hcnt2 = 0u; gok1 = 0u; gok2 = 0u; }
  __syncthreads();  // only full-block sync

  float* const big = ws + BIG_OFF;
  float* const hbuf = ws + HBUF_OFF;
  float* const hrg = ws + HR_OFF;
  const float* const att = ws + ATT_OFF;
  unsigned* const fbase = (unsigned*)(ws + FLAGS_OFF);
  unsigned* const af1 = fbase + 256 + (bg << 7);
  unsigned* const af2 = fbase + 512 + (bg << 7);

  const int wv = tid >> 6, l = tid & 63, q = wv & 3;
  const int boff = b0 + 2 * l;

  if (wv < 4) {
    // ---- x-waves: one pass over sseq[t], 3 x-projections ----
    const float* const wrx = wr_s + ((size_t)q << 10) + 512;
    const float* const wux = wu_s + ((size_t)q << 10) + 512;
    const float* const whx = wh_s + ((size_t)q << 10) + 512;
    for (int u = 0; u < NL; ++u) {
      if (u >= 4) lds_wait(&xcons, 4u * (unsigned)(u - 3));
      const float* const xp = big + (size_t)u * SLICE + boff;  // sseqT[u], read-only -> normal/L2
      float a00 = 0, a01 = 0, a10 = 0, a11 = 0, a20 = 0, a21 = 0;
      for (int gg = 0; gg < 16; ++gg) {
        float2 v[32];
#pragma unroll
        for (int j = 0; j < 32; ++j) v[j] = *(const float2*)(xp + (size_t)(gg * 32 + j) * 256);
#pragma unroll
        for (int j = 0; j < 32; ++j) {
          const int k = gg * 32 + j;
          const float u0 = wrx[k], u1 = wux[k], u2 = whx[k];
          a00 += v[j].x * u0; a01 += v[j].y * u0;
          a10 += v[j].x * u1; a11 += v[j].y * u1;
          a20 += v[j].x * u2; a21 += v[j].y * u2;
        }
      }
      float* const xo = &xbuf[u & 3][0][0][0];
      *(float2*)(xo + (0 * 4 + q) * 128 + 2 * l) = make_float2(a00, a01);
      *(float2*)(xo + (1 * 4 + q) * 128 + 2 * l) = make_float2(a10, a11);
      *(float2*)(xo + (2 * 4 + q) * 128 + 2 * l) = make_float2(a20, a21);
      lds_sig(&xdone);
    }
  } else {
    // ---- h-waves: 2-phase recurrence ----
    const float* const wrh = wr_s + ((size_t)q << 10);
    const float* const wuh = wu_s + ((size_t)q << 10);
    const float* const whh_ = wh_s + ((size_t)q << 10);
    const size_t o = (size_t)(c0 + q) * 256 + boff;
    for (int t = 0; t < NL; ++t) {
      if (t > 0) {
        if (wv == 4) {
          gwait(af2, (unsigned)t);
          if (l == 0)
            __hip_atomic_store(&gok2, (unsigned)t, __ATOMIC_RELAXED, __HIP_MEMORY_SCOPE_WORKGROUP);
        } else {
          lds_wait(&gok2, (unsigned)t);
        }
      }
      const float* const hbase = (t == 0) ? (big + 199ul * SLICE)
                                          : (hbuf + (size_t)(t & 1) * SLICE);
      float pr0 = 0, pr1 = 0, pu0 = 0, pu1 = 0;
      {
        const float* const hp = hbase + boff;
        for (int gg = 0; gg < 16; ++gg) {
          float2 v[32];
#pragma unroll
          for (int j = 0; j < 32; ++j) v[j] = cohld2(hp + (size_t)(gg * 32 + j) * 256);
#pragma unroll
          for (int j = 0; j < 32; ++j) {
            const int k = gg * 32 + j;
            const float ur = wrh[k], uu = wuh[k];
            pr0 += v[j].x * ur; pr1 += v[j].y * ur;
            pu0 += v[j].x * uu; pu1 += v[j].y * uu;
          }
        }
      }
      const float2 hcur = cohld2(hbase + o);
      lds_wait(&xdone, 4u * (unsigned)(t + 1));
      const float* const xo = &xbuf[t & 3][0][0][0];
      const float2 xr = *(const float2*)(xo + (0 * 4 + q) * 128 + 2 * l);
      const float2 xu = *(const float2*)(xo + (1 * 4 + q) * 128 + 2 * l);
      const float2 xh = *(const float2*)(xo + (2 * 4 + q) * 128 + 2 * l);
      lds_sig(&xcons);
      const float rg0 = sigmoidf_(pr0 + xr.x + rbs[q]);
      const float rg1 = sigmoidf_(pr1 + xr.y + rbs[q]);
      const float ug0 = sigmoidf_(pu0 + xu.x + ubs[q]);
      const float ug1 = sigmoidf_(pu1 + xu.y + ubs[q]);
      cohst2(hrg + o, make_float2(rg0 * hcur.x, rg1 * hcur.y));
      asm volatile("s_waitcnt vmcnt(0)" ::: "memory");
      if (l == 0)
        __hip_atomic_fetch_add(&hcnt1, 1u, __ATOMIC_RELAXED, __HIP_MEMORY_SCOPE_WORKGROUP);
      if (wv == 4) {
        if (l == 0) {
          int guard = 0;
          while (__hip_atomic_load(&hcnt1, __ATOMIC_RELAXED, __HIP_MEMORY_SCOPE_WORKGROUP)
                 < 4u * (unsigned)(t + 1)) {
            if (++guard > (1 << 25)) break;
          }
          __hip_atomic_store(af1 + ng, (unsigned)(t + 1), __ATOMIC_RELAXED, __HIP_MEMORY_SCOPE_AGENT);
        }
        gwait(af1, (unsigned)(t + 1));
        if (l == 0)
          __hip_atomic_store(&gok1, (unsigned)(t + 1), __ATOMIC_RELAXED, __HIP_MEMORY_SCOPE_WORKGROUP);
      } else {
        lds_wait(&gok1, (unsigned)(t + 1));
      }
      // phase 2: hhat
      float ph0 = 0, ph1 = 0;
      {
        const float* const rp = hrg + boff;
        for (int gg = 0; gg < 16; ++gg) {
          float2 v[32];
#pragma unroll
          for (int j = 0; j < 32; ++j) v[j] = cohld2(rp + (size_t)(gg * 32 + j) * 256);
#pragma unroll
          for (int j = 0; j < 32; ++j) {
            const float uh = whh_[gg * 32 + j];
            ph0 += v[j].x * uh; ph1 += v[j].y * uh;
          }
        }
      }
      const float hh0 = tanhf(ph0 + xh.x + hbs[q]);
      const float hh1 = tanhf(ph1 + xh.y + hbs[q]);
      const float2 av = *(const float2*)(att + (size_t)t * 256 + boff);
      const float uu0 = av.x * ug0, uu1 = av.y * ug1;
      const float hn0 = (1.0f - uu0) * hcur.x + uu0 * hh0;
      const float hn1 = (1.0f - uu1) * hcur.y + uu1 * hh1;
      if (t == NL - 1) {
        out[(size_t)boff * 512 + c0 + q] = hn0;
        out[(size_t)(boff + 1) * 512 + c0 + q] = hn1;
      } else {
        cohst2(hbuf + (size_t)((t + 1) & 1) * SLICE + o, make_float2(hn0, hn1));
      }
      asm volatile("s_waitcnt vmcnt(0)" ::: "memory");
      if (l == 0)
        __hip_atomic_fetch_add(&hcnt2, 1u, __ATOMIC_RELAXED, __HIP_MEMORY_SCOPE_WORKGROUP);
      if (wv == 4 && l == 0) {
        int guard = 0;
        while (__hip_atomic_load(&hcnt2, __ATOMIC_RELAXED, __HIP_MEMORY_SCOPE_WORKGROUP)
               < 4u * (unsigned)(t + 1)) {
          if (++guard > (1 << 25)) break;
        }
        __hip_atomic_store(af2 + ng, (unsigned)(t + 1), __ATOMIC_RELAXED, __HIP_MEMORY_SCOPE_AGENT);
      }
    }
  }
}

extern "C" void kernel_launch(void* const* d_in, const int* in_sizes, int n_in,
                              void* d_out, int out_size, void* d_ws, size_t ws_size,
                              hipStream_t stream) {
  (void)in_sizes; (void)n_in; (void)out_size; (void)ws_size;
  const float* session = (const float*)d_in[0];
  const float* target  = (const float*)d_in[1];
  const float* w       = (const float*)d_in[2];
  const float* wih     = (const float*)d_in[3];
  const float* whh     = (const float*)d_in[4];
  const float* bih     = (const float*)d_in[5];
  const float* bhh     = (const float*)d_in[6];
  const float* rw      = (const float*)d_in[7];
  const float* rb      = (const float*)d_in[8];
  const float* uw      = (const float*)d_in[9];
  const float* ub      = (const float*)d_in[10];
  const float* hw      = (const float*)d_in[11];
  const float* hb      = (const float*)d_in[12];
  float* ws  = (float*)d_ws;
  float* out = (float*)d_out;

  hipLaunchKernelGGL(init_kernel, dim3(1), dim3(256), 0, stream, ws);
  hipLaunchKernelGGL(transpose_kernel, dim3(1600, 4), dim3(256), 0, stream, session, ws);
  hipLaunchKernelGGL(vt_kernel, dim3(256), dim3(256), 0, stream, w, target, ws);
  hipLaunchKernelGGL(gru_kernel, dim3(256), dim3(512), 0, stream,
                     wih, whh, bih, bhh, ws);
  hipLaunchKernelGGL(attn1_kernel, dim3(200), dim3(256), 0, stream, ws);
  hipLaunchKernelGGL(attn2_kernel, dim3(256), dim3(256), 0, stream, ws);
  hipLaunchKernelGGL(augru_kernel, dim3(256), dim3(512), 0, stream,
                     rw, rb, uw, ub, hw, hb, ws, out);
}

// Round 6
// 7192.039 us; speedup vs baseline: 6.1492x; 2.5018x over previous
//
#include <hip/hip_runtime.h>
#include <math.h>

#define NL 200
#define SLICE 131072ul  // 512 k * 256 b floats

// ---- workspace layout (float offsets), activations stored [k][b] ----
// BIG[201][512][256]: slice u+1 = sessionT[u]; GRU writes h_t = sseqT[t] at slice t.
#define BIG_OFF   0ul
#define LG_OFF    26345472ul   // logits [200][256]
#define ATT_OFF   26396672ul   // att    [200][256]
#define VT_OFF    26447872ul   // vtT    [512][256]
#define HBUF_OFF  26578944ul   // AUGRU h ping-pong [2][512][256]
#define HR_OFF    26841088ul   // r*h [512][256]
#define FLAGS_OFF 26972160ul   // u32 flags: gf[2][128] @0, af1[4][64] @256, af2[4][64] @512

__device__ __forceinline__ float sigmoidf_(float x) { return 1.0f / (1.0f + expf(-x)); }

// ---- LLC-direct (sc1) accessors: relaxed agent atomics, no fences ----
__device__ __forceinline__ float cohld1(const float* p) {
  return __hip_atomic_load(p, __ATOMIC_RELAXED, __HIP_MEMORY_SCOPE_AGENT);
}
__device__ __forceinline__ float2 cohld2(const float* p) {
  union { double d; float2 f; } u;
  u.d = __hip_atomic_load((const double*)p, __ATOMIC_RELAXED, __HIP_MEMORY_SCOPE_AGENT);
  return u.f;
}
__device__ __forceinline__ void cohst1(float* p, float v) {
  __hip_atomic_store(p, v, __ATOMIC_RELAXED, __HIP_MEMORY_SCOPE_AGENT);
}

// ---- grid waits: one wave polls flags (per-lane exit; wave exits when all lanes do) ----
__device__ __forceinline__ void gwait64(const unsigned* f, unsigned val) {
  const int i = threadIdx.x & 63;
  int guard = 0;
  while (__hip_atomic_load(f + i, __ATOMIC_RELAXED, __HIP_MEMORY_SCOPE_AGENT) < val) {
    if (++guard > (1 << 22)) break;  // deadlock escape
  }
}
__device__ __forceinline__ void gwait128(const unsigned* f, unsigned val) {
  const int i = threadIdx.x & 63;
  bool d0 = false, d1 = false;
  int guard = 0;
  while (!(d0 && d1)) {
    if (!d0) d0 = __hip_atomic_load(f + i, __ATOMIC_RELAXED, __HIP_MEMORY_SCOPE_AGENT) >= val;
    if (!d1) d1 = __hip_atomic_load(f + i + 64, __ATOMIC_RELAXED, __HIP_MEMORY_SCOPE_AGENT) >= val;
    if (++guard > (1 << 22)) break;
  }
}

// ---- init: zero flags (graph replays => rerun every call) ----
__global__ void init_kernel(float* __restrict__ ws) {
  unsigned* const fl = (unsigned*)(ws + FLAGS_OFF);
  for (int j = threadIdx.x; j < 768; j += 256) fl[j] = 0u;
}

// ---- transpose session -> BIG slices 1..200 as [k][b] (sc1 stores) ----
__global__ __launch_bounds__(256) void transpose_kernel(const float* __restrict__ in,
                                                        float* __restrict__ ws) {
  __shared__ float tile[64][65];
  const int tx = threadIdx.x & 63, ty = threadIdx.x >> 6;
  const size_t tk0 = (size_t)blockIdx.x * 64;
  const int b0 = blockIdx.y * 64;
#pragma unroll
  for (int r = 0; r < 16; ++r) {
    const int bb = ty + 4 * r;
    tile[bb][tx] = in[(size_t)(b0 + bb) * 102400 + tk0 + tx];
  }
  __syncthreads();
  float* const big1 = ws + BIG_OFF + SLICE;
#pragma unroll
  for (int r = 0; r < 16; ++r) {
    const int kk = ty + 4 * r;
    cohst1(big1 + (tk0 + kk) * 256 + b0 + tx, tile[tx][kk]);
  }
}

// ---- vtT[d][b] = sum_e w[d,e] * target[b,e] ----
__global__ __launch_bounds__(256) void vt_kernel(const float* __restrict__ w,
                                                 const float* __restrict__ tgt,
                                                 float* __restrict__ ws) {
  __shared__ float t_s[512];
  const int b = blockIdx.x, tid = threadIdx.x;
  for (int i = tid; i < 512; i += 256) t_s[i] = tgt[(size_t)b * 512 + i];
  __syncthreads();
  const int wv = tid >> 6, lane = tid & 63;
  for (int d = wv; d < 512; d += 4) {
    const float* const wr = w + (size_t)d * 512;
    const float4 a  = *(const float4*)(wr + lane * 8);
    const float4 a2 = *(const float4*)(wr + lane * 8 + 4);
    float s = a.x * t_s[lane * 8 + 0] + a.y * t_s[lane * 8 + 1] +
              a.z * t_s[lane * 8 + 2] + a.w * t_s[lane * 8 + 3] +
              a2.x * t_s[lane * 8 + 4] + a2.y * t_s[lane * 8 + 5] +
              a2.z * t_s[lane * 8 + 6] + a2.w * t_s[lane * 8 + 7];
    for (int off = 32; off > 0; off >>= 1) s += __shfl_xor(s, off);
    if (lane == 0) ws[VT_OFF + (size_t)d * 256 + b] = s;
  }
}

// ---- persistent GRU: 2 halves x 128 col-groups; split-k over 8 waves ----
// Per block: 4 cols x 128 rows. Wave wv owns k in [64wv,64wv+64). LDS reduce.
__global__ __launch_bounds__(512) void gru_kernel(const float* __restrict__ wih,
                                                  const float* __restrict__ whh,
                                                  const float* __restrict__ bih,
                                                  const float* __restrict__ bhh,
                                                  float* __restrict__ ws) {
  __shared__ float wxT[512 * 16];   // [k][16]: slot g*4+q (12 used), broadcast reads
  __shared__ float whT[512 * 16];
  __shared__ float red[16 * 8 * 130];  // [slot][wave][128 rows +2 pad]
  __shared__ float bihs[12], bhhs[12];

  const int bg = blockIdx.x >> 7;   // batch half
  const int ng = blockIdx.x & 127;  // col group
  const int b0 = bg << 7, c0 = ng << 2;
  const int tid = threadIdx.x;

  for (int i = tid; i < 512 * 16; i += 512) {
    const int k = i >> 4, s = i & 15;
    if (s < 12) {
      const int grow = ((s >> 2) << 9) + c0 + (s & 3);
      wxT[i] = wih[(size_t)grow * 512 + k];
      whT[i] = whh[(size_t)grow * 512 + k];
    }
  }
  if (tid < 12) {
    const int grow = ((tid >> 2) << 9) + c0 + (tid & 3);
    bihs[tid] = bih[grow];
    bhhs[tid] = bhh[grow];
  }
  __syncthreads();

  float* const big = ws + BIG_OFF;
  unsigned* const gf = (unsigned*)(ws + FLAGS_OFF) + (bg << 7);

  const int wv = tid >> 6, l = tid & 63;
  const int k0 = wv << 6;
  const int boff = b0 + 2 * l;          // dot-stage: rows 2l,2l+1 (float2)
  const int qg = tid >> 7;              // gate-stage: col qg, row rr
  const int rr = tid & 127;
  const size_t og = (size_t)(c0 + qg) * 256 + b0 + rr;

  for (int t = 0; t < NL; ++t) {
    // ---- x-dot (sc1 loads; session slice t+1) ----
    const float* const xp = big + (size_t)(t + 1) * SLICE + boff;
    float2 ax[12];
#pragma unroll
    for (int s = 0; s < 12; ++s) ax[s] = make_float2(0.0f, 0.0f);
    for (int bq = 0; bq < 4; ++bq) {
      const int kb = k0 + bq * 16;
      float2 v[16];
#pragma unroll
      for (int j = 0; j < 16; ++j) v[j] = cohld2(xp + (size_t)(kb + j) * 256);
#pragma unroll
      for (int j = 0; j < 16; ++j) {
        const float4* const wr = (const float4*)(wxT + (size_t)(kb + j) * 16);
        float w12[12];
        *(float4*)&w12[0] = wr[0];
        *(float4*)&w12[4] = wr[1];
        *(float4*)&w12[8] = wr[2];
#pragma unroll
        for (int s = 0; s < 12; ++s) {
          ax[s].x += v[j].x * w12[s];
          ax[s].y += v[j].y * w12[s];
        }
      }
    }
    // ---- grid wait ----
    if (t > 0) {
      if (wv == 0) gwait128(gf, (unsigned)t);
      __syncthreads();
    }
    // ---- h-dot (normal loads; fresh addresses each step -> L2-shared) ----
    float2 ah[12];
#pragma unroll
    for (int s = 0; s < 12; ++s) ah[s] = make_float2(0.0f, 0.0f);
    float hprev = 0.0f;
    if (t > 0) {
      const float* const hp = big + (size_t)(t - 1) * SLICE + boff;
      hprev = big[(size_t)(t - 1) * SLICE + og];  // prefetch for gate stage
      for (int bq = 0; bq < 4; ++bq) {
        const int kb = k0 + bq * 16;
        float2 v[16];
#pragma unroll
        for (int j = 0; j < 16; ++j) v[j] = *(const float2*)(hp + (size_t)(kb + j) * 256);
#pragma unroll
        for (int j = 0; j < 16; ++j) {
          const float4* const wr = (const float4*)(whT + (size_t)(kb + j) * 16);
          float w12[12];
          *(float4*)&w12[0] = wr[0];
          *(float4*)&w12[4] = wr[1];
          *(float4*)&w12[8] = wr[2];
#pragma unroll
          for (int s = 0; s < 12; ++s) {
            ah[s].x += v[j].x * w12[s];
            ah[s].y += v[j].y * w12[s];
          }
        }
      }
    }
    // ---- cross-wave reduce: slots 0-3 r(x+h), 4-7 z(x+h), 8-11 xn, 12-15 hn ----
#pragma unroll
    for (int s = 0; s < 4; ++s) {
      *(float2*)&red[((size_t)(0 + s) * 8 + wv) * 130 + 2 * l] =
          make_float2(ax[s].x + ah[s].x, ax[s].y + ah[s].y);
      *(float2*)&red[((size_t)(4 + s) * 8 + wv) * 130 + 2 * l] =
          make_float2(ax[4 + s].x + ah[4 + s].x, ax[4 + s].y + ah[4 + s].y);
      *(float2*)&red[((size_t)(8 + s) * 8 + wv) * 130 + 2 * l] = ax[8 + s];
      *(float2*)&red[((size_t)(12 + s) * 8 + wv) * 130 + 2 * l] = ah[8 + s];
    }
    __syncthreads();
    // ---- gates: thread -> (col qg, row rr) ----
    float rp = 0, zp = 0, xnp = 0, hnp = 0;
#pragma unroll
    for (int w8 = 0; w8 < 8; ++w8) {
      rp  += red[((size_t)(0 + qg) * 8 + w8) * 130 + rr];
      zp  += red[((size_t)(4 + qg) * 8 + w8) * 130 + rr];
      xnp += red[((size_t)(8 + qg) * 8 + w8) * 130 + rr];
      hnp += red[((size_t)(12 + qg) * 8 + w8) * 130 + rr];
    }
    const float r = sigmoidf_(rp + bihs[0 + qg] + bhhs[0 + qg]);
    const float z = sigmoidf_(zp + bihs[4 + qg] + bhhs[4 + qg]);
    const float n = tanhf(xnp + bihs[8 + qg] + r * (hnp + bhhs[8 + qg]));
    const float hnew = (1.0f - z) * n + z * hprev;
    cohst1(big + (size_t)t * SLICE + og, hnew);
    // ---- arrive ----
    asm volatile("s_waitcnt vmcnt(0)" ::: "memory");
    __syncthreads();
    if (tid == 0)
      __hip_atomic_store(gf + ng, (unsigned)(t + 1), __ATOMIC_RELAXED, __HIP_MEMORY_SCOPE_AGENT);
  }
}

// ---- attn1: logits[l][b] = sum_k sseqT[l][k][b] * vtT[k][b] ----
__global__ __launch_bounds__(256) void attn1_kernel(float* __restrict__ ws) {
  const int l = blockIdx.x, tid = threadIdx.x;
  const float* const sl = ws + BIG_OFF + (size_t)l * SLICE + tid;
  const float* const vtt = ws + VT_OFF + tid;
  float acc = 0.0f;
#pragma unroll 8
  for (int k = 0; k < 512; ++k)
    acc += sl[(size_t)k * 256] * vtt[(size_t)k * 256];
  ws[LG_OFF + (size_t)l * 256 + tid] = acc;
}

// ---- attn2: softmax over l per batch row; write attT[l][b] ----
__global__ __launch_bounds__(256) void attn2_kernel(float* __restrict__ ws) {
  __shared__ float red[8];
  const int b = blockIdx.x, tid = threadIdx.x;
  const float v = (tid < NL) ? ws[LG_OFF + (size_t)tid * 256 + b] : -3.0e38f;
  float m = v;
  for (int off = 32; off > 0; off >>= 1) m = fmaxf(m, __shfl_xor(m, off));
  if ((tid & 63) == 0) red[tid >> 6] = m;
  __syncthreads();
  m = fmaxf(fmaxf(red[0], red[1]), fmaxf(red[2], red[3]));
  const float e = (tid < NL) ? expf(v - m) : 0.0f;
  float s = e;
  for (int off = 32; off > 0; off >>= 1) s += __shfl_xor(s, off);
  __syncthreads();
  if ((tid & 63) == 0) red[4 + (tid >> 6)] = s;
  __syncthreads();
  s = red[4] + red[5] + red[6] + red[7];
  if (tid < NL) ws[ATT_OFF + (size_t)tid * 256 + b] = e / s;
}

// ---- persistent AUGRU: 4 row-groups x 64 col-groups; split-k over 8 waves ----
// Per block: 8 cols x 64 rows. x=sseq normal; h/hr sc1 ping-pong.
__global__ __launch_bounds__(512) void augru_kernel(const float* __restrict__ rw,
                                                    const float* __restrict__ rbias,
                                                    const float* __restrict__ uw,
                                                    const float* __restrict__ ubias,
                                                    const float* __restrict__ hw,
                                                    const float* __restrict__ hbias,
                                                    float* __restrict__ ws,
                                                    float* __restrict__ out) {
  __shared__ float wT[1024 * 24];     // [k][24]: slot m*8+c (m: 0=r,1=u,2=hhat)
  __shared__ float red[24 * 8 * 66];  // [slot][wave][64 rows +2 pad]
  __shared__ float rbs[8], ubs[8], hbs[8];

  const int rg = blockIdx.x >> 6;   // row group (64 rows)
  const int cg = blockIdx.x & 63;   // col group (8 cols)
  const int r0 = rg << 6, c0 = cg << 3;
  const int tid = threadIdx.x;

  for (int m = 0; m < 3; ++m) {
    const float* const wm = (m == 0) ? rw : (m == 1) ? uw : hw;
    for (int i = tid; i < 8192; i += 512) {
      const int k = i >> 3, c = i & 7;
      wT[(size_t)k * 24 + m * 8 + c] = wm[(size_t)(c0 + c) * 1024 + k];
    }
  }
  if (tid < 8) {
    rbs[tid] = rbias[c0 + tid];
    ubs[tid] = ubias[c0 + tid];
    hbs[tid] = hbias[c0 + tid];
  }
  __syncthreads();

  float* const big = ws + BIG_OFF;
  float* const hbuf = ws + HBUF_OFF;
  float* const hrg = ws + HR_OFF;
  const float* const att = ws + ATT_OFF;
  unsigned* const fbase = (unsigned*)(ws + FLAGS_OFF);
  unsigned* const af1 = fbase + 256 + (rg << 6);
  unsigned* const af2 = fbase + 512 + (rg << 6);

  const int wv = tid >> 6, l = tid & 63;
  const int k0 = wv << 6;
  const int boff = r0 + l;            // dot-stage: 1 row per lane
  const int cq = tid >> 6;            // gate-stage: col cq, row rr
  const int rr = tid & 63;
  const size_t og = (size_t)(c0 + cq) * 256 + r0 + rr;

  for (int t = 0; t < NL; ++t) {
    // ---- x-dot: all 3 mats, one pass (normal loads; sseq final) ----
    const float* const xp = big + (size_t)t * SLICE + boff;
    float ax[24];
#pragma unroll
    for (int s = 0; s < 24; ++s) ax[s] = 0.0f;
    for (int bq = 0; bq < 4; ++bq) {
      const int kb = k0 + bq * 16;
      float v[16];
#pragma unroll
      for (int j = 0; j < 16; ++j) v[j] = xp[(size_t)(kb + j) * 256];
#pragma unroll
      for (int j = 0; j < 16; ++j) {
        const float4* const wr = (const float4*)(wT + (size_t)(512 + kb + j) * 24);
        float w24[24];
        *(float4*)&w24[0] = wr[0];  *(float4*)&w24[4] = wr[1];
        *(float4*)&w24[8] = wr[2];  *(float4*)&w24[12] = wr[3];
        *(float4*)&w24[16] = wr[4]; *(float4*)&w24[20] = wr[5];
#pragma unroll
        for (int s = 0; s < 24; ++s) ax[s] += v[j] * w24[s];
      }
    }
    // ---- wait previous step's phase2 ----
    if (t > 0) {
      if (wv == 0) gwait64(af2, (unsigned)t);
      __syncthreads();
    }
    // ---- phase1 h-dot: r,u (sc1; h src = GRU final at t=0, else ping-pong) ----
    const float* const hsrc = (t == 0) ? (big + 199ul * SLICE) : (hbuf + (size_t)(t & 1) * SLICE);
    const float hcur = cohld1(hsrc + og);
    float ah[16];
#pragma unroll
    for (int s = 0; s < 16; ++s) ah[s] = 0.0f;
    {
      const float* const hp = hsrc + boff;
      for (int bq = 0; bq < 4; ++bq) {
        const int kb = k0 + bq * 16;
        float v[16];
#pragma unroll
        for (int j = 0; j < 16; ++j) v[j] = cohld1(hp + (size_t)(kb + j) * 256);
#pragma unroll
        for (int j = 0; j < 16; ++j) {
          const float4* const wr = (const float4*)(wT + (size_t)(kb + j) * 24);
          float w16[16];
          *(float4*)&w16[0] = wr[0];  *(float4*)&w16[4] = wr[1];
          *(float4*)&w16[8] = wr[2];  *(float4*)&w16[12] = wr[3];
#pragma unroll
          for (int s = 0; s < 16; ++s) ah[s] += v[j] * w16[s];
        }
      }
    }
    // ---- reduce phase1: slots 0-7 r(x+h), 8-15 u(x+h), 16-23 xh ----
#pragma unroll
    for (int c = 0; c < 8; ++c) {
      red[((size_t)(0 + c) * 8 + wv) * 66 + l] = ax[c] + ah[c];
      red[((size_t)(8 + c) * 8 + wv) * 66 + l] = ax[8 + c] + ah[8 + c];
      red[((size_t)(16 + c) * 8 + wv) * 66 + l] = ax[16 + c];
    }
    __syncthreads();
    float rp = 0, up = 0, xhp = 0;
#pragma unroll
    for (int w8 = 0; w8 < 8; ++w8) {
      rp  += red[((size_t)(0 + cq) * 8 + w8) * 66 + rr];
      up  += red[((size_t)(8 + cq) * 8 + w8) * 66 + rr];
      xhp += red[((size_t)(16 + cq) * 8 + w8) * 66 + rr];
    }
    const float rgate = sigmoidf_(rp + rbs[cq]);
    const float ug = sigmoidf_(up + ubs[cq]);
    cohst1(hrg + og, rgate * hcur);
    asm volatile("s_waitcnt vmcnt(0)" ::: "memory");
    __syncthreads();
    if (tid == 0)
      __hip_atomic_store(af1 + cg, (unsigned)(t + 1), __ATOMIC_RELAXED, __HIP_MEMORY_SCOPE_AGENT);
    if (wv == 0) gwait64(af1, (unsigned)(t + 1));
    __syncthreads();
    // ---- phase2 hr-dot: hhat (sc1) ----
    float ahh[8];
#pragma unroll
    for (int s = 0; s < 8; ++s) ahh[s] = 0.0f;
    {
      const float* const rp2 = hrg + boff;
      for (int bq = 0; bq < 4; ++bq) {
        const int kb = k0 + bq * 16;
        float v[16];
#pragma unroll
        for (int j = 0; j < 16; ++j) v[j] = cohld1(rp2 + (size_t)(kb + j) * 256);
#pragma unroll
        for (int j = 0; j < 16; ++j) {
          const float4* const wr = (const float4*)(wT + (size_t)(kb + j) * 24);
          float w8a[8];
          *(float4*)&w8a[0] = wr[4];
          *(float4*)&w8a[4] = wr[5];
#pragma unroll
          for (int s = 0; s < 8; ++s) ahh[s] += v[j] * w8a[s];
        }
      }
    }
#pragma unroll
    for (int c = 0; c < 8; ++c)
      red[((size_t)c * 8 + wv) * 66 + l] = ahh[c];
    __syncthreads();
    float hhp = 0;
#pragma unroll
    for (int w8 = 0; w8 < 8; ++w8)
      hhp += red[((size_t)cq * 8 + w8) * 66 + rr];
    const float hh = tanhf(hhp + xhp + hbs[cq]);
    const float av = att[(size_t)t * 256 + r0 + rr];
    const float u = av * ug;
    const float hn = (1.0f - u) * hcur + u * hh;
    if (t == NL - 1) {
      out[(size_t)(r0 + rr) * 512 + c0 + cq] = hn;
    } else {
      cohst1(hbuf + (size_t)((t + 1) & 1) * SLICE + og, hn);
    }
    asm volatile("s_waitcnt vmcnt(0)" ::: "memory");
    __syncthreads();
    if (tid == 0)
      __hip_atomic_store(af2 + cg, (unsigned)(t + 1), __ATOMIC_RELAXED, __HIP_MEMORY_SCOPE_AGENT);
  }
}

extern "C" void kernel_launch(void* const* d_in, const int* in_sizes, int n_in,
                              void* d_out, int out_size, void* d_ws, size_t ws_size,
                              hipStream_t stream) {
  (void)in_sizes; (void)n_in; (void)out_size; (void)ws_size;
  const float* session = (const float*)d_in[0];
  const float* target  = (const float*)d_in[1];
  const float* w       = (const float*)d_in[2];
  const float* wih     = (const float*)d_in[3];
  const float* whh     = (const float*)d_in[4];
  const float* bih     = (const float*)d_in[5];
  const float* bhh     = (const float*)d_in[6];
  const float* rw      = (const float*)d_in[7];
  const float* rb      = (const float*)d_in[8];
  const float* uw      = (const float*)d_in[9];
  const float* ub      = (const float*)d_in[10];
  const float* hw      = (const float*)d_in[11];
  const float* hb      = (const float*)d_in[12];
  float* ws  = (float*)d_ws;
  float* out = (float*)d_out;

  hipLaunchKernelGGL(init_kernel, dim3(1), dim3(256), 0, stream, ws);
  hipLaunchKernelGGL(transpose_kernel, dim3(1600, 4), dim3(256), 0, stream, session, ws);
  hipLaunchKernelGGL(vt_kernel, dim3(256), dim3(256), 0, stream, w, target, ws);
  hipLaunchKernelGGL(gru_kernel, dim3(256), dim3(512), 0, stream,
                     wih, whh, bih, bhh, ws);
  hipLaunchKernelGGL(attn1_kernel, dim3(200), dim3(256), 0, stream, ws);
  hipLaunchKernelGGL(attn2_kernel, dim3(256), dim3(256), 0, stream, ws);
  hipLaunchKernelGGL(augru_kernel, dim3(256), dim3(512), 0, stream,
                     rw, rb, uw, ub, hw, hb, ws, out);
}